// Round 7
// baseline (2578.582 us; speedup 1.0000x reference)
//
#include <hip/hip_runtime.h>
#include <hip/hip_bf16.h>
#include <math.h>

#define KNN 16
#define CIN 128
#define COUT 128
#define D2 64
#define EPS 1e-5f

typedef __attribute__((ext_vector_type(8))) short short8;
typedef __attribute__((ext_vector_type(4))) float f32x4;
typedef __attribute__((ext_vector_type(2))) unsigned int u32x2;
typedef unsigned int u32;
typedef unsigned short u16;

union S8U { short8 s; u32 u[4]; };

#define MFMA16(a, b, c) __builtin_amdgcn_mfma_f32_16x16x32_bf16((a), (b), (c), 0, 0, 0)

static __device__ __forceinline__ u16 f2bf(float f) {
  __hip_bfloat16 h = __float2bfloat16(f);
  u16 u; __builtin_memcpy(&u, &h, 2); return u;
}
#if __has_builtin(__builtin_amdgcn_cvt_pk_bf16_f32)
static __device__ __forceinline__ u32 pack2(float a, float b) {
  auto r = __builtin_amdgcn_cvt_pk_bf16_f32(a, b);  // v_cvt_pk_bf16_f32 (gfx950)
  u32 u; __builtin_memcpy(&u, &r, 4); return u;
}
#else
static __device__ __forceinline__ u32 pack2(float a, float b) {
  return (u32)f2bf(a) | ((u32)f2bf(b) << 16);
}
#endif
static __device__ __forceinline__ float bf_lo(u32 u) { return __uint_as_float(u << 16); }
static __device__ __forceinline__ float bf_hi(u32 u) { return __uint_as_float(u & 0xffff0000u); }

// gelu(x) ~= x * sigmoid(1.702 x); 1.702*log2(e) = 2.4555331
static __device__ __forceinline__ float gelu_fast(float x) {
  float e = __builtin_amdgcn_exp2f(x * -2.4555331f);
  return x * __builtin_amdgcn_rcpf(1.0f + e);
}

// max-reduce over the 16-lane DPP row (lanes l..l|15)
template <int CTRL>
static __device__ __forceinline__ float dppmax(float v) {
  int s = __builtin_bit_cast(int, v);
  int t = __builtin_amdgcn_update_dpp(s, s, CTRL, 0xf, 0xf, true);
  return fmaxf(v, __builtin_bit_cast(float, t));
}
static __device__ __forceinline__ float rowmax16(float v) {
  v = dppmax<0xB1>(v);   // quad_perm xor1
  v = dppmax<0x4E>(v);   // quad_perm xor2
  v = dppmax<0x141>(v);  // row_half_mirror
  v = dppmax<0x128>(v);  // row_ror:8
  return v;
}

// ---- in-register C-layout -> B-frag transpose (replaces LDS scratch) ----
// Input: 4 u32 bf16-pairs per lane; M[g][x] with g = lane>>4 (16-lane group),
//   x = h*2+jj2 (a0=h0/lo, a1=h0/hi, a2=h1/lo, a3=h1/hi).
// Output short8 u[k] = M[2*(g&1) + (k>>1)][2*(g>>1) + (k&1)]  -- exactly the
// layout the old sliced-scratch write+read produced (verified vs m*80 layout).
static __device__ __forceinline__ short8 xpose4(u32 a0, u32 a1, u32 a2, u32 a3) {
#if __has_builtin(__builtin_amdgcn_permlane32_swap) && __has_builtin(__builtin_amdgcn_permlane16_swap)
  u32x2 r02 = __builtin_amdgcn_permlane32_swap(a0, a2, false, false);
  u32x2 r13 = __builtin_amdgcn_permlane32_swap(a1, a3, false, false);
  u32x2 s02 = __builtin_amdgcn_permlane16_swap(r02.x, r02.y, false, false);
  u32x2 s13 = __builtin_amdgcn_permlane16_swap(r13.x, r13.y, false, false);
  S8U o;
  o.u[0] = s02.x; o.u[1] = s13.x; o.u[2] = s02.y; o.u[3] = s13.y;
  return o.s;
#else
  // generic butterfly fallback (shfl_xor + select), same mapping
  const int lane = (int)(threadIdx.x & 63);
  const bool lo32 = lane < 32;
  const bool even16 = (lane & 16) == 0;
  u32 a0p = lo32 ? a0 : (u32)__shfl_xor((int)a2, 32, 64);
  u32 a2p = lo32 ? (u32)__shfl_xor((int)a0, 32, 64) : a2;
  u32 a1p = lo32 ? a1 : (u32)__shfl_xor((int)a3, 32, 64);
  u32 a3p = lo32 ? (u32)__shfl_xor((int)a1, 32, 64) : a3;
  u32 t0 = even16 ? a0p : (u32)__shfl_xor((int)a2p, 16, 64);
  u32 t2 = even16 ? (u32)__shfl_xor((int)a0p, 16, 64) : a2p;
  u32 t1 = even16 ? a1p : (u32)__shfl_xor((int)a3p, 16, 64);
  u32 t3 = even16 ? (u32)__shfl_xor((int)a1p, 16, 64) : a3p;
  S8U o;
  o.u[0] = t0; o.u[1] = t1; o.u[2] = t2; o.u[3] = t3;
  return o.s;
#endif
}

// ---------- k_proj: xp = x @ W via MFMA (xp^T tiles), bf16-pair output ----------
__global__ __launch_bounds__(256) void k_proj(const float* __restrict__ x,
                                              const float* __restrict__ W,
                                              u32* __restrict__ xp, int n) {
  __shared__ __align__(16) u32 Wf[8192];  // 32 frags (8 mt x 4 ks) x 256 u32
  const int t = threadIdx.x;
  for (int idx = t; idx < 8192; idx += 256) {
    int f = idx >> 8, rem = idx & 255;
    int l = rem >> 2, jp = rem & 3;
    int mt = f >> 2, ks = f & 3;
    int qq = l >> 4, mm = l & 15;
    int k = ks * 32 + qq * 8 + jp * 2;
    int c = mt * 16 + mm;
    Wf[idx] = pack2(W[(size_t)k * COUT + c], W[(size_t)(k + 1) * COUT + c]);
  }
  __syncthreads();

  const int wv = t >> 6, l = t & 63;
  const int q = l >> 4, m = l & 15;
  const short8* Wf8 = (const short8*)Wf;

  for (int tile = blockIdx.x * 4 + wv; tile * 16 < n; tile += gridDim.x * 4) {
    int r0 = tile * 16;
    int rr = min(r0 + m, n - 1);
    const float4* xr = (const float4*)(x + (size_t)rr * CIN);
    S8U xf[4];
#pragma unroll
    for (int ks = 0; ks < 4; ks++) {
      float4 a = xr[ks * 8 + q * 2];
      float4 b = xr[ks * 8 + q * 2 + 1];
      xf[ks].u[0] = pack2(a.x, a.y);
      xf[ks].u[1] = pack2(a.z, a.w);
      xf[ks].u[2] = pack2(b.x, b.y);
      xf[ks].u[3] = pack2(b.z, b.w);
    }
    bool ok = (r0 + m) < n;
    size_t rowb = (size_t)(r0 + m) * 64;
#pragma unroll
    for (int mt = 0; mt < 8; mt++) {
      f32x4 acc = {0.f, 0.f, 0.f, 0.f};
#pragma unroll
      for (int ks = 0; ks < 4; ks++)
        acc = MFMA16(Wf8[(mt * 4 + ks) * 64 + l], xf[ks].s, acc);
      if (ok) {
        uint2 v;
        v.x = pack2(acc[0], acc[1]);
        v.y = pack2(acc[2], acc[3]);
        *(uint2*)&xp[rowb + mt * 8 + q * 2] = v;
      }
    }
  }
}

// ---------- k_lfa: MFMA fused NCA + gather + max ----------
// v7 (resubmit after infra failure): ONE point per wave. Five rounds of
// evidence: the allocator always lands on a 64-VGPR budget for this kernel
// (every launch_bounds / waves_per_eu variant), and the 2-point xpose4 live
// set (~100 regs) spills GBs at 64. 1-pt live set peaks at ~62 regs -> fits
// 64 natively, zero spill. Same per-point MFMA count; af LDS reads double
// (cheap, overlaps MFMA). 1024-thr blocks + 76 KB LDS -> 2 blocks/CU -> at
// VGPR=64 the HW runs 32 waves/CU = 8 waves/SIMD: 2x round-1 occupancy.
__global__ __launch_bounds__(1024, 2) void k_lfa(
    const float* __restrict__ xyz, const u32* __restrict__ xp,
    const int* __restrict__ knn,
    const float* __restrict__ m1w, const float* __restrict__ m1b,
    const float* __restrict__ m2w, const float* __restrict__ m2b,
    const float* __restrict__ m3aw, const float* __restrict__ m3ab,
    const float* __restrict__ m3bw, const float* __restrict__ m3bb,
    float* __restrict__ xsmax, int n) {
  // [0,73728) frags (m2 f0..7, m3a f8..39, m3b f40..71), [73728,74752) w14,
  // [74752,76032) biases
  __shared__ __align__(16) char lds[76032];

  const int t = threadIdx.x, wv = t >> 6, l = t & 63;
  const int q = l >> 4, m = l & 15;

  {  // ---- per-block weight pack
    u32* lds32 = (u32*)lds;
    for (int idx = t; idx < 18432; idx += 1024) {
      int f = idx >> 8, rem = idx & 255;
      int ll = rem >> 2, jp = rem & 3;
      int qq = ll >> 4, mm = ll & 15;
      int j0 = jp * 2;
      float a, b;
      if (f < 8) {
        int mt = f >> 1, s = f & 1;
        const float* p = m2w + (size_t)(s * 32 + qq * 8 + j0) * D2 + mt * 16 + mm;
        a = p[0]; b = p[D2];
      } else if (f < 40) {
        int ff = f - 8; int mt = ff >> 2, s = ff & 3;
        const float* p = m3aw + (size_t)(s * 32 + qq * 8 + j0) * COUT + mt * 16 + mm;
        a = p[0]; b = p[COUT];
      } else {
        int ff = f - 40; int mt = ff >> 2, s = ff & 3;
        const float* p = m3bw + (size_t)(s * 32 + qq * 8 + j0) * COUT + mt * 16 + mm;
        a = p[0]; b = p[COUT];
      }
      lds32[idx] = pack2(a, b);
    }
    if (t < 64) {
      int p = (t & 32) + (t & 7) * 4 + ((t >> 3) & 3);
      ((float4*)(lds + 73728))[p] = make_float4(m1w[t], m1w[64 + t], m1w[128 + t], m1b[t]);
    }
    if (t < 320) {
      float* bias = (float*)(lds + 74752);
      bias[t] = (t < 64) ? m2b[t] : (t < 192) ? m3ab[t - 64] : m3bb[t - 192];
    }
  }
  __syncthreads();

  const char* fr = lds;
  const float4* w14 = (const float4*)(lds + 73728);
  const float* bias = (const float*)(lds + 74752);

  for (int pt = blockIdx.x * 16 + wv; pt < n; pt += gridDim.x * 16) {
    const int kid = knn[(size_t)pt * KNN + m];

    // ---- prefetch epilogue gathers: 8 scattered 8B loads (16 VGPR) with
    // the whole NCA MLP (~72 MFMAs) as cover. Pure loads: worst case the
    // compiler sinks them (never spills them).
    uint2 g[8];
#pragma unroll
    for (int mt = 0; mt < 8; mt++)
      g[mt] = *(const uint2*)(xp + (size_t)kid * 64 + mt * 8 + q * 2);

    float px = xyz[pt * 3 + 0], py = xyz[pt * 3 + 1], pz = xyz[pt * 3 + 2];
    float ax = xyz[kid * 3 + 0] - px, ay = xyz[kid * 3 + 1] - py, az = xyz[kid * 3 + 2] - pz;

    // ---- p0 rows in B-frag layout (registers)
    float p0[16];
#pragma unroll
    for (int s = 0; s < 2; s++)
#pragma unroll
      for (int j = 0; j < 8; j++) {
        float4 w = w14[s * 32 + j * 4 + q];
        p0[s * 8 + j] = fmaf(ax, w.x, fmaf(ay, w.y, fmaf(az, w.z, w.w)));
      }
    S8U bp0[2], bpl[2];
#pragma unroll
    for (int s = 0; s < 2; s++)
#pragma unroll
      for (int jj = 0; jj < 4; jj++)
        bp0[s].u[jj] = pack2(p0[s * 8 + 2 * jj], p0[s * 8 + 2 * jj + 1]);
#pragma unroll
    for (int i = 0; i < 16; i++) p0[i] = rowmax16(p0[i]);
#pragma unroll
    for (int s = 0; s < 2; s++)
#pragma unroll
      for (int jj = 0; jj < 4; jj++)
        bpl[s].u[jj] = pack2(p0[s * 8 + 2 * jj], p0[s * 8 + 2 * jj + 1]);

    // ---- m2 -> p1 -> bpf frags (in-register transpose)
    short8 bpf[2];
#pragma unroll
    for (int s = 0; s < 2; s++) {
      u32 u[4];
#pragma unroll
      for (int h = 0; h < 2; h++) {
        int mt = 2 * s + h;
        float4 bb = *(const float4*)&bias[mt * 16 + q * 4];
        f32x4 acc = {bb.x, bb.y, bb.z, bb.w};
#pragma unroll
        for (int ks = 0; ks < 2; ks++) {
          short8 af = *(const short8*)(fr + (mt * 2 + ks) * 1024 + l * 16);
          acc = MFMA16(af, bp0[ks].s, acc);
        }
        u[h * 2 + 0] = pack2(acc[0], acc[1]);
        u[h * 2 + 1] = pack2(acc[2], acc[3]);
      }
      bpf[s] = xpose4(u[0], u[1], u[2], u[3]);
    }

    // ---- m3a -> gelu -> bg frags (in-register transpose)
    short8 bg[4];
#pragma unroll
    for (int s = 0; s < 4; s++) {
      u32 u[4];
#pragma unroll
      for (int h = 0; h < 2; h++) {
        int mt = 2 * s + h;
        float4 bb = *(const float4*)&bias[64 + mt * 16 + q * 4];
        f32x4 acc = {bb.x, bb.y, bb.z, bb.w};
#pragma unroll
        for (int ks = 0; ks < 4; ks++) {
          short8 af = *(const short8*)(fr + (8 + mt * 4 + ks) * 1024 + l * 16);
          short8 b = (ks == 0) ? bpf[0] : (ks == 1) ? bpf[1] : (ks == 2) ? bpl[0].s : bpl[1].s;
          acc = MFMA16(af, b, acc);
        }
        u[h * 2 + 0] = pack2(gelu_fast(acc[0]), gelu_fast(acc[1]));
        u[h * 2 + 1] = pack2(gelu_fast(acc[2]), gelu_fast(acc[3]));
      }
      bg[s] = xpose4(u[0], u[1], u[2], u[3]);
    }

    // ---- m3b + fused epilogue (gathers prefetched in g[])
#pragma unroll
    for (int mt = 0; mt < 8; mt++) {
      float4 bb = *(const float4*)&bias[192 + mt * 16 + q * 4];
      f32x4 acc = {bb.x, bb.y, bb.z, bb.w};
#pragma unroll
      for (int ks = 0; ks < 4; ks++) {
        short8 af = *(const short8*)(fr + (40 + mt * 4 + ks) * 1024 + l * 16);
        acc = MFMA16(af, bg[ks], acc);
      }
      // self-row load: uniform in m -> broadcast; issued before the rowmax
      // chain so its latency hides under the 32 DPP-max ops.
      uint2 sf = *(const uint2*)(xp + (size_t)pt * 64 + mt * 8 + q * 2);
      float v0 = bf_lo(g[mt].x) + acc[0];
      float v1 = bf_hi(g[mt].x) + acc[1];
      float v2 = bf_lo(g[mt].y) + acc[2];
      float v3 = bf_hi(g[mt].y) + acc[3];
      v0 = rowmax16(v0); v1 = rowmax16(v1); v2 = rowmax16(v2); v3 = rowmax16(v3);
      if (m == 0) {
        float4 o = make_float4(v0 - bf_lo(sf.x), v1 - bf_hi(sf.x),
                               v2 - bf_lo(sf.y), v3 - bf_hi(sf.y));
        *(float4*)&xsmax[(size_t)pt * COUT + mt * 16 + q * 4] = o;
      }
    }
  }
}

// ---------- BN stage 1: per-block partial sums ----------
__global__ __launch_bounds__(256) void k_bnstats(const float* __restrict__ xs,
                                                 float* __restrict__ part, int n) {
  int t = threadIdx.x;
  int c = t & 127;
  int h = t >> 7;
  float s = 0.f, s2 = 0.f;
  for (int r = blockIdx.x * 2 + h; r < n; r += gridDim.x * 2) {
    float v = xs[(size_t)r * COUT + c];
    s += v;
    s2 += v * v;
  }
  __shared__ float red[256];
  red[t] = s;
  __syncthreads();
  if (h == 0) part[blockIdx.x * 256 + c] = s + red[t + 128];
  __syncthreads();
  red[t] = s2;
  __syncthreads();
  if (h == 0) part[blockIdx.x * 256 + 128 + c] = s2 + red[t + 128];
}

// ---------- BN stage 2: finalize mean/invstd (parallel over 8 part-slices) ----------
__global__ __launch_bounds__(1024) void k_bnfinal(const float* __restrict__ part,
                                                  float* __restrict__ ms,
                                                  int n, int nb) {
  __shared__ float red[2048];
  int t = threadIdx.x;
  int c = t & 127;   // channel
  int h = t >> 7;    // 8 slices over the nb partial blocks
  float s = 0.f, s2 = 0.f;
  for (int b = h; b < nb; b += 8) {
    s += part[b * 256 + c];
    s2 += part[b * 256 + 128 + c];
  }
  red[t] = s;
  red[1024 + t] = s2;
  __syncthreads();
  if (h == 0) {
#pragma unroll
    for (int k = 1; k < 8; k++) {
      s += red[k * 128 + c];
      s2 += red[1024 + k * 128 + c];
    }
    float inv_n = 1.0f / (float)n;
    float mean = s * inv_n;
    float var = s2 * inv_n - mean * mean;
    ms[c] = mean;
    ms[128 + c] = rsqrtf(var + EPS);
  }
}

// ---------- BN normalize ----------
__global__ __launch_bounds__(256) void k_bnnorm(const float* __restrict__ xs,
                                                const float* __restrict__ ms,
                                                const float* __restrict__ gamma,
                                                const float* __restrict__ beta,
                                                float* __restrict__ out, int n) {
  size_t i = (size_t)blockIdx.x * 256 + threadIdx.x;
  size_t total4 = (size_t)n * (COUT / 4);
  if (i >= total4) return;
  int c = (int)((i * 4) & (COUT - 1));
  float4 v = ((const float4*)xs)[i];
  float4 mn = *(const float4*)&ms[c];
  float4 iv = *(const float4*)&ms[128 + c];
  float4 gm = *(const float4*)&gamma[c];
  float4 bt = *(const float4*)&beta[c];
  float4 o;
  o.x = (v.x - mn.x) * iv.x * gm.x + bt.x;
  o.y = (v.y - mn.y) * iv.y * gm.y + bt.y;
  o.z = (v.z - mn.z) * iv.z * gm.z + bt.z;
  o.w = (v.w - mn.w) * iv.w * gm.w + bt.w;
  ((float4*)out)[i] = o;
}

// ---------- launch ----------
extern "C" void kernel_launch(void* const* d_in, const int* in_sizes, int n_in,
                              void* d_out, int out_size, void* d_ws, size_t ws_size,
                              hipStream_t stream) {
  const float* xyz = (const float*)d_in[0];
  const float* x = (const float*)d_in[1];
  const int* knn = (const int*)d_in[2];
  const float* W = (const float*)d_in[3];
  const float* m1w = (const float*)d_in[4];
  const float* m1b = (const float*)d_in[5];
  const float* m2w = (const float*)d_in[6];
  const float* m2b = (const float*)d_in[7];
  const float* m3aw = (const float*)d_in[8];
  const float* m3ab = (const float*)d_in[9];
  const float* m3bw = (const float*)d_in[10];
  const float* m3bb = (const float*)d_in[11];
  const float* gamma = (const float*)d_in[12];
  const float* beta = (const float*)d_in[13];
  float* out = (float*)d_out;

  int n = in_sizes[0] / 3;

  char* ws = (char*)d_ws;
  u32* xp = (u32*)ws;                       // n * 256 B
  size_t o1 = (((size_t)n * 256 + 255) & ~(size_t)255);
  float* xsm = (float*)(ws + o1);           // n * 512 B
  size_t o2 = o1 + (((size_t)n * 512 + 255) & ~(size_t)255);
  float* part = (float*)(ws + o2);          // 512 blocks * 256 floats
  size_t o3 = o2 + 524288;
  float* ms = (float*)(ws + o3);            // 256 floats (mean | invstd)

  k_proj<<<512, 256, 0, stream>>>(x, W, xp, n);
  k_lfa<<<512, 1024, 0, stream>>>(xyz, xp, knn, m1w, m1b, m2w, m2b,
                                  m3aw, m3ab, m3bw, m3bb, xsm, n);
  k_bnstats<<<512, 256, 0, stream>>>(xsm, part, n);
  k_bnfinal<<<1, 1024, 0, stream>>>(part, ms, n, 512);
  k_bnnorm<<<(int)(((size_t)n * (COUT / 4) + 255) / 256), 256, 0, stream>>>(
      xsm, ms, gamma, beta, out, n);
}

// Round 8
// 483.692 us; speedup vs baseline: 5.3310x; 5.3310x over previous
//
#include <hip/hip_runtime.h>
#include <hip/hip_bf16.h>
#include <math.h>

#define KNN 16
#define CIN 128
#define COUT 128
#define D2 64
#define EPS 1e-5f

typedef __attribute__((ext_vector_type(8))) short short8;
typedef __attribute__((ext_vector_type(4))) float f32x4;
typedef unsigned int u32;
typedef unsigned short u16;

union S8U { short8 s; u32 u[4]; };

#define MFMA16(a, b, c) __builtin_amdgcn_mfma_f32_16x16x32_bf16((a), (b), (c), 0, 0, 0)

static __device__ __forceinline__ u16 f2bf(float f) {
  __hip_bfloat16 h = __float2bfloat16(f);
  u16 u; __builtin_memcpy(&u, &h, 2); return u;
}
#if __has_builtin(__builtin_amdgcn_cvt_pk_bf16_f32)
static __device__ __forceinline__ u32 pack2(float a, float b) {
  auto r = __builtin_amdgcn_cvt_pk_bf16_f32(a, b);  // v_cvt_pk_bf16_f32 (gfx950)
  u32 u; __builtin_memcpy(&u, &r, 4); return u;
}
#else
static __device__ __forceinline__ u32 pack2(float a, float b) {
  return (u32)f2bf(a) | ((u32)f2bf(b) << 16);
}
#endif
static __device__ __forceinline__ float bf_lo(u32 u) { return __uint_as_float(u << 16); }
static __device__ __forceinline__ float bf_hi(u32 u) { return __uint_as_float(u & 0xffff0000u); }

// gelu(x) ~= x * sigmoid(1.702 x); 1.702*log2(e) = 2.4555331
static __device__ __forceinline__ float gelu_fast(float x) {
  float e = __builtin_amdgcn_exp2f(x * -2.4555331f);
  return x * __builtin_amdgcn_rcpf(1.0f + e);
}

// max-reduce over the 16-lane DPP row (lanes l..l|15)
template <int CTRL>
static __device__ __forceinline__ float dppmax(float v) {
  int s = __builtin_bit_cast(int, v);
  int t = __builtin_amdgcn_update_dpp(s, s, CTRL, 0xf, 0xf, true);
  return fmaxf(v, __builtin_bit_cast(float, t));
}
static __device__ __forceinline__ float rowmax16(float v) {
  v = dppmax<0xB1>(v);   // quad_perm xor1
  v = dppmax<0x4E>(v);   // quad_perm xor2
  v = dppmax<0x141>(v);  // row_half_mirror
  v = dppmax<0x128>(v);  // row_ror:8
  return v;
}

// ---------- k_proj: xp = x @ W via MFMA (xp^T tiles), bf16-pair output ----------
// A = W^T frags (LDS, packed per block), B = x-row frags (registers).
// C-layout: lane (q,m) -> point m of the 16-row tile, channels mt*16+q*4+r.
__global__ __launch_bounds__(256) void k_proj(const float* __restrict__ x,
                                              const float* __restrict__ W,
                                              u32* __restrict__ xp, int n) {
  __shared__ __align__(16) u32 Wf[8192];  // 32 frags (8 mt x 4 ks) x 256 u32
  const int t = threadIdx.x;
  for (int idx = t; idx < 8192; idx += 256) {
    int f = idx >> 8, rem = idx & 255;
    int l = rem >> 2, jp = rem & 3;
    int mt = f >> 2, ks = f & 3;
    int qq = l >> 4, mm = l & 15;
    int k = ks * 32 + qq * 8 + jp * 2;
    int c = mt * 16 + mm;
    Wf[idx] = pack2(W[(size_t)k * COUT + c], W[(size_t)(k + 1) * COUT + c]);
  }
  __syncthreads();

  const int wv = t >> 6, l = t & 63;
  const int q = l >> 4, m = l & 15;
  const short8* Wf8 = (const short8*)Wf;

  for (int tile = blockIdx.x * 4 + wv; tile * 16 < n; tile += gridDim.x * 4) {
    int r0 = tile * 16;
    int rr = min(r0 + m, n - 1);
    const float4* xr = (const float4*)(x + (size_t)rr * CIN);
    S8U xf[4];
#pragma unroll
    for (int ks = 0; ks < 4; ks++) {
      float4 a = xr[ks * 8 + q * 2];
      float4 b = xr[ks * 8 + q * 2 + 1];
      xf[ks].u[0] = pack2(a.x, a.y);
      xf[ks].u[1] = pack2(a.z, a.w);
      xf[ks].u[2] = pack2(b.x, b.y);
      xf[ks].u[3] = pack2(b.z, b.w);
    }
    bool ok = (r0 + m) < n;
    size_t rowb = (size_t)(r0 + m) * 64;
#pragma unroll
    for (int mt = 0; mt < 8; mt++) {
      f32x4 acc = {0.f, 0.f, 0.f, 0.f};
      __builtin_amdgcn_s_setprio(1);
#pragma unroll
      for (int ks = 0; ks < 4; ks++)
        acc = MFMA16(Wf8[(mt * 4 + ks) * 64 + l], xf[ks].s, acc);
      __builtin_amdgcn_s_setprio(0);
      if (ok) {
        uint2 v;
        v.x = pack2(acc[0], acc[1]);
        v.y = pack2(acc[2], acc[3]);
        *(uint2*)&xp[rowb + mt * 8 + q * 2] = v;
      }
    }
  }
}

// ---------- k_lfa: MFMA fused NCA + gather + max ----------
// v8 = r1 restored verbatim (the only zero-spill config: VGPR=64, FETCH
// 227 MB, k_lfa 342 us) + s_setprio around MFMA clusters (T5).
// Lessons burned into this structure:
//  - allocator budget is immovably 64 VGPR for this kernel; every
//    register-resident transpose variant (r2-r7) spilled 3-5 GB.
//  - frag A-operands MUST stream from LDS (7 GB of re-reads; only LDS
//    BW covers it), so 117 KB LDS -> 16 waves/CU is the structural cap.
//  - main loop has NO barrier: waves run phase-independent, the regime
//    where setprio pays (m191). Zero register-pressure impact.
__global__ __launch_bounds__(1024, 4) void k_lfa(
    const float* __restrict__ xyz, const u32* __restrict__ xp,
    const int* __restrict__ knn,
    const float* __restrict__ m1w, const float* __restrict__ m1b,
    const float* __restrict__ m2w, const float* __restrict__ m2b,
    const float* __restrict__ m3aw, const float* __restrict__ m3ab,
    const float* __restrict__ m3bw, const float* __restrict__ m3bb,
    float* __restrict__ xsmax, int n) {
  // [0,73728) frags (m2 f0..7, m3a f8..39, m3b f40..71), [73728,74752) w14,
  // [74752,76032) biases, [76032,116992) per-wave scratch 16 x 2560 B
  __shared__ __align__(16) char lds[116992];

  const int t = threadIdx.x, wv = t >> 6, l = t & 63;
  const int q = l >> 4, m = l & 15;

  {  // ---- per-block weight pack
    u32* lds32 = (u32*)lds;
    for (int idx = t; idx < 18432; idx += 1024) {
      int f = idx >> 8, rem = idx & 255;
      int ll = rem >> 2, jp = rem & 3;
      int qq = ll >> 4, mm = ll & 15;
      int j0 = jp * 2;
      float a, b;
      if (f < 8) {
        int mt = f >> 1, s = f & 1;
        const float* p = m2w + (size_t)(s * 32 + qq * 8 + j0) * D2 + mt * 16 + mm;
        a = p[0]; b = p[D2];
      } else if (f < 40) {
        int ff = f - 8; int mt = ff >> 2, s = ff & 3;
        const float* p = m3aw + (size_t)(s * 32 + qq * 8 + j0) * COUT + mt * 16 + mm;
        a = p[0]; b = p[COUT];
      } else {
        int ff = f - 40; int mt = ff >> 2, s = ff & 3;
        const float* p = m3bw + (size_t)(s * 32 + qq * 8 + j0) * COUT + mt * 16 + mm;
        a = p[0]; b = p[COUT];
      }
      lds32[idx] = pack2(a, b);
    }
    if (t < 64) {
      int p = (t & 32) + (t & 7) * 4 + ((t >> 3) & 3);
      ((float4*)(lds + 73728))[p] = make_float4(m1w[t], m1w[64 + t], m1w[128 + t], m1b[t]);
    }
    if (t < 320) {
      float* bias = (float*)(lds + 74752);
      bias[t] = (t < 64) ? m2b[t] : (t < 192) ? m3ab[t - 64] : m3bb[t - 192];
    }
  }
  __syncthreads();

  const char* fr = lds;
  const float4* w14 = (const float4*)(lds + 73728);
  const float* bias = (const float*)(lds + 74752);
  char* sA = lds + 76032 + wv * 2560;
  char* sB = sA + 1280;

  for (int pr = blockIdx.x * 16 + wv; pr * 2 < n; pr += gridDim.x * 16) {
    const int ptA = pr * 2;
    const int ptB = ptA + 1;
    const bool hasB = ptB < n;
    const int ptBc = hasB ? ptB : ptA;
    const int kidA = knn[(size_t)ptA * KNN + m];
    const int kidB = knn[(size_t)ptBc * KNN + m];

    // ---- prefetch epilogue gathers (compiler may sink; harmless)
    uint2 gA[8], gB[8];
#pragma unroll
    for (int mt = 0; mt < 8; mt++) {
      gA[mt] = *(const uint2*)(xp + (size_t)kidA * 64 + mt * 8 + q * 2);
      gB[mt] = *(const uint2*)(xp + (size_t)kidB * 64 + mt * 8 + q * 2);
    }

    float pxA = xyz[ptA * 3 + 0], pyA = xyz[ptA * 3 + 1], pzA = xyz[ptA * 3 + 2];
    float pxB = xyz[ptBc * 3 + 0], pyB = xyz[ptBc * 3 + 1], pzB = xyz[ptBc * 3 + 2];
    float axA = xyz[kidA * 3 + 0] - pxA, ayA = xyz[kidA * 3 + 1] - pyA, azA = xyz[kidA * 3 + 2] - pzA;
    float axB = xyz[kidB * 3 + 0] - pxB, ayB = xyz[kidB * 3 + 1] - pyB, azB = xyz[kidB * 3 + 2] - pzB;

    // ---- p0 rows in B-frag layout (registers)
    float p0A[16], p0B[16];
#pragma unroll
    for (int s = 0; s < 2; s++)
#pragma unroll
      for (int j = 0; j < 8; j++) {
        float4 w = w14[s * 32 + j * 4 + q];
        p0A[s * 8 + j] = fmaf(axA, w.x, fmaf(ayA, w.y, fmaf(azA, w.z, w.w)));
        p0B[s * 8 + j] = fmaf(axB, w.x, fmaf(ayB, w.y, fmaf(azB, w.z, w.w)));
      }
    S8U bp0A[2], bp0B[2], bplA[2], bplB[2];
#pragma unroll
    for (int s = 0; s < 2; s++)
#pragma unroll
      for (int jj = 0; jj < 4; jj++) {
        bp0A[s].u[jj] = pack2(p0A[s * 8 + 2 * jj], p0A[s * 8 + 2 * jj + 1]);
        bp0B[s].u[jj] = pack2(p0B[s * 8 + 2 * jj], p0B[s * 8 + 2 * jj + 1]);
      }
#pragma unroll
    for (int i = 0; i < 16; i++) { p0A[i] = rowmax16(p0A[i]); p0B[i] = rowmax16(p0B[i]); }
#pragma unroll
    for (int s = 0; s < 2; s++)
#pragma unroll
      for (int jj = 0; jj < 4; jj++) {
        bplA[s].u[jj] = pack2(p0A[s * 8 + 2 * jj], p0A[s * 8 + 2 * jj + 1]);
        bplB[s].u[jj] = pack2(p0B[s * 8 + 2 * jj], p0B[s * 8 + 2 * jj + 1]);
      }

    // ---- m2 -> p1 (sliced scratch) -> bpf frags
    short8 bpfA[2], bpfB[2];
#pragma unroll
    for (int s = 0; s < 2; s++) {
#pragma unroll
      for (int h = 0; h < 2; h++) {
        int mt = 2 * s + h;
        float4 bb = *(const float4*)&bias[mt * 16 + q * 4];
        f32x4 accA = {bb.x, bb.y, bb.z, bb.w};
        f32x4 accB = accA;
        __builtin_amdgcn_s_setprio(1);
#pragma unroll
        for (int ks = 0; ks < 2; ks++) {
          short8 af = *(const short8*)(fr + (mt * 2 + ks) * 1024 + l * 16);
          accA = MFMA16(af, bp0A[ks].s, accA);
          accB = MFMA16(af, bp0B[ks].s, accB);
        }
        __builtin_amdgcn_s_setprio(0);
        uint2 wA; wA.x = pack2(accA[0], accA[1]); wA.y = pack2(accA[2], accA[3]);
        uint2 wB; wB.x = pack2(accB[0], accB[1]); wB.y = pack2(accB[2], accB[3]);
        *(uint2*)(sA + m * 80 + h * 32 + q * 8) = wA;
        *(uint2*)(sB + m * 80 + h * 32 + q * 8) = wB;
      }
      bpfA[s] = *(const short8*)(sA + m * 80 + q * 16);
      bpfB[s] = *(const short8*)(sB + m * 80 + q * 16);
    }

    // ---- m3a -> gelu -> g (sliced scratch) -> bg frags
    short8 bgA[4], bgB[4];
#pragma unroll
    for (int s = 0; s < 4; s++) {
#pragma unroll
      for (int h = 0; h < 2; h++) {
        int mt = 2 * s + h;
        float4 bb = *(const float4*)&bias[64 + mt * 16 + q * 4];
        f32x4 accA = {bb.x, bb.y, bb.z, bb.w};
        f32x4 accB = accA;
        __builtin_amdgcn_s_setprio(1);
#pragma unroll
        for (int ks = 0; ks < 4; ks++) {
          short8 af = *(const short8*)(fr + (8 + mt * 4 + ks) * 1024 + l * 16);
          short8 bA = (ks == 0) ? bpfA[0] : (ks == 1) ? bpfA[1] : (ks == 2) ? bplA[0].s : bplA[1].s;
          short8 bB = (ks == 0) ? bpfB[0] : (ks == 1) ? bpfB[1] : (ks == 2) ? bplB[0].s : bplB[1].s;
          accA = MFMA16(af, bA, accA);
          accB = MFMA16(af, bB, accB);
        }
        __builtin_amdgcn_s_setprio(0);
        uint2 wA; wA.x = pack2(gelu_fast(accA[0]), gelu_fast(accA[1]));
        wA.y = pack2(gelu_fast(accA[2]), gelu_fast(accA[3]));
        uint2 wB; wB.x = pack2(gelu_fast(accB[0]), gelu_fast(accB[1]));
        wB.y = pack2(gelu_fast(accB[2]), gelu_fast(accB[3]));
        *(uint2*)(sA + m * 80 + h * 32 + q * 8) = wA;
        *(uint2*)(sB + m * 80 + h * 32 + q * 8) = wB;
      }
      bgA[s] = *(const short8*)(sA + m * 80 + q * 16);
      bgB[s] = *(const short8*)(sB + m * 80 + q * 16);
    }

    // ---- m3b + fused epilogue (pe in regs; gathers in gA/gB)
#pragma unroll
    for (int mt = 0; mt < 8; mt++) {
      float4 bb = *(const float4*)&bias[192 + mt * 16 + q * 4];
      f32x4 accA = {bb.x, bb.y, bb.z, bb.w};
      f32x4 accB = accA;
      __builtin_amdgcn_s_setprio(1);
#pragma unroll
      for (int ks = 0; ks < 4; ks++) {
        short8 af = *(const short8*)(fr + (40 + mt * 4 + ks) * 1024 + l * 16);
        accA = MFMA16(af, bgA[ks], accA);
        accB = MFMA16(af, bgB[ks], accB);
      }
      __builtin_amdgcn_s_setprio(0);
      {
        // self-row load: uniform in m -> broadcast; issued before the rowmax
        // chain so its latency hides under the DPP-max ops.
        uint2 sf = *(const uint2*)(xp + (size_t)ptA * 64 + mt * 8 + q * 2);
        float v0 = bf_lo(gA[mt].x) + accA[0];
        float v1 = bf_hi(gA[mt].x) + accA[1];
        float v2 = bf_lo(gA[mt].y) + accA[2];
        float v3 = bf_hi(gA[mt].y) + accA[3];
        v0 = rowmax16(v0); v1 = rowmax16(v1); v2 = rowmax16(v2); v3 = rowmax16(v3);
        if (m == 0) {
          float4 o = make_float4(v0 - bf_lo(sf.x), v1 - bf_hi(sf.x),
                                 v2 - bf_lo(sf.y), v3 - bf_hi(sf.y));
          *(float4*)&xsmax[(size_t)ptA * COUT + mt * 16 + q * 4] = o;
        }
      }
      {
        uint2 sf = *(const uint2*)(xp + (size_t)ptBc * 64 + mt * 8 + q * 2);
        float v0 = bf_lo(gB[mt].x) + accB[0];
        float v1 = bf_hi(gB[mt].x) + accB[1];
        float v2 = bf_lo(gB[mt].y) + accB[2];
        float v3 = bf_hi(gB[mt].y) + accB[3];
        v0 = rowmax16(v0); v1 = rowmax16(v1); v2 = rowmax16(v2); v3 = rowmax16(v3);
        if (hasB && m == 0) {
          float4 o = make_float4(v0 - bf_lo(sf.x), v1 - bf_hi(sf.x),
                                 v2 - bf_lo(sf.y), v3 - bf_hi(sf.y));
          *(float4*)&xsmax[(size_t)ptB * COUT + mt * 16 + q * 4] = o;
        }
      }
    }
  }
}

// ---------- BN stage 1: per-block partial sums ----------
__global__ __launch_bounds__(256) void k_bnstats(const float* __restrict__ xs,
                                                 float* __restrict__ part, int n) {
  int t = threadIdx.x;
  int c = t & 127;
  int h = t >> 7;
  float s = 0.f, s2 = 0.f;
  for (int r = blockIdx.x * 2 + h; r < n; r += gridDim.x * 2) {
    float v = xs[(size_t)r * COUT + c];
    s += v;
    s2 += v * v;
  }
  __shared__ float red[256];
  red[t] = s;
  __syncthreads();
  if (h == 0) part[blockIdx.x * 256 + c] = s + red[t + 128];
  __syncthreads();
  red[t] = s2;
  __syncthreads();
  if (h == 0) part[blockIdx.x * 256 + 128 + c] = s2 + red[t + 128];
}

// ---------- BN stage 2: finalize mean/invstd (parallel over 8 part-slices) ----------
__global__ __launch_bounds__(1024) void k_bnfinal(const float* __restrict__ part,
                                                  float* __restrict__ ms,
                                                  int n, int nb) {
  __shared__ float red[2048];
  int t = threadIdx.x;
  int c = t & 127;   // channel
  int h = t >> 7;    // 8 slices over the nb partial blocks
  float s = 0.f, s2 = 0.f;
  for (int b = h; b < nb; b += 8) {
    s += part[b * 256 + c];
    s2 += part[b * 256 + 128 + c];
  }
  red[t] = s;
  red[1024 + t] = s2;
  __syncthreads();
  if (h == 0) {
#pragma unroll
    for (int k = 1; k < 8; k++) {
      s += red[k * 128 + c];
      s2 += red[1024 + k * 128 + c];
    }
    float inv_n = 1.0f / (float)n;
    float mean = s * inv_n;
    float var = s2 * inv_n - mean * mean;
    ms[c] = mean;
    ms[128 + c] = rsqrtf(var + EPS);
  }
}

// ---------- BN normalize ----------
__global__ __launch_bounds__(256) void k_bnnorm(const float* __restrict__ xs,
                                                const float* __restrict__ ms,
                                                const float* __restrict__ gamma,
                                                const float* __restrict__ beta,
                                                float* __restrict__ out, int n) {
  size_t i = (size_t)blockIdx.x * 256 + threadIdx.x;
  size_t total4 = (size_t)n * (COUT / 4);
  if (i >= total4) return;
  int c = (int)((i * 4) & (COUT - 1));
  float4 v = ((const float4*)xs)[i];
  float4 mn = *(const float4*)&ms[c];
  float4 iv = *(const float4*)&ms[128 + c];
  float4 gm = *(const float4*)&gamma[c];
  float4 bt = *(const float4*)&beta[c];
  float4 o;
  o.x = (v.x - mn.x) * iv.x * gm.x + bt.x;
  o.y = (v.y - mn.y) * iv.y * gm.y + bt.y;
  o.z = (v.z - mn.z) * iv.z * gm.z + bt.z;
  o.w = (v.w - mn.w) * iv.w * gm.w + bt.w;
  ((float4*)out)[i] = o;
}

// ---------- launch ----------
extern "C" void kernel_launch(void* const* d_in, const int* in_sizes, int n_in,
                              void* d_out, int out_size, void* d_ws, size_t ws_size,
                              hipStream_t stream) {
  const float* xyz = (const float*)d_in[0];
  const float* x = (const float*)d_in[1];
  const int* knn = (const int*)d_in[2];
  const float* W = (const float*)d_in[3];
  const float* m1w = (const float*)d_in[4];
  const float* m1b = (const float*)d_in[5];
  const float* m2w = (const float*)d_in[6];
  const float* m2b = (const float*)d_in[7];
  const float* m3aw = (const float*)d_in[8];
  const float* m3ab = (const float*)d_in[9];
  const float* m3bw = (const float*)d_in[10];
  const float* m3bb = (const float*)d_in[11];
  const float* gamma = (const float*)d_in[12];
  const float* beta = (const float*)d_in[13];
  float* out = (float*)d_out;

  int n = in_sizes[0] / 3;

  char* ws = (char*)d_ws;
  u32* xp = (u32*)ws;                       // n * 256 B
  size_t o1 = (((size_t)n * 256 + 255) & ~(size_t)255);
  float* xsm = (float*)(ws + o1);           // n * 512 B
  size_t o2 = o1 + (((size_t)n * 512 + 255) & ~(size_t)255);
  float* part = (float*)(ws + o2);          // 512 blocks * 256 floats
  size_t o3 = o2 + 524288;
  float* ms = (float*)(ws + o3);            // 256 floats (mean | invstd)

  k_proj<<<512, 256, 0, stream>>>(x, W, xp, n);
  k_lfa<<<256, 1024, 0, stream>>>(xyz, xp, knn, m1w, m1b, m2w, m2b,
                                  m3aw, m3ab, m3bw, m3bb, xsm, n);
  k_bnstats<<<512, 256, 0, stream>>>(xsm, part, n);
  k_bnfinal<<<1, 1024, 0, stream>>>(part, ms, n, 512);
  k_bnnorm<<<(int)(((size_t)n * (COUT / 4) + 255) / 256), 256, 0, stream>>>(
      xsm, ms, gamma, beta, out, n);
}

// Round 9
// 473.188 us; speedup vs baseline: 5.4494x; 1.0222x over previous
//
#include <hip/hip_runtime.h>
#include <hip/hip_bf16.h>
#include <math.h>

#define KNN 16
#define CIN 128
#define COUT 128
#define D2 64
#define EPS 1e-5f

typedef __attribute__((ext_vector_type(8))) short short8;
typedef __attribute__((ext_vector_type(4))) float f32x4;
typedef unsigned int u32;
typedef unsigned short u16;

union S8U { short8 s; u32 u[4]; };

#define MFMA16(a, b, c) __builtin_amdgcn_mfma_f32_16x16x32_bf16((a), (b), (c), 0, 0, 0)

static __device__ __forceinline__ u16 f2bf(float f) {
  __hip_bfloat16 h = __float2bfloat16(f);
  u16 u; __builtin_memcpy(&u, &h, 2); return u;
}
#if __has_builtin(__builtin_amdgcn_cvt_pk_bf16_f32)
static __device__ __forceinline__ u32 pack2(float a, float b) {
  auto r = __builtin_amdgcn_cvt_pk_bf16_f32(a, b);  // v_cvt_pk_bf16_f32 (gfx950)
  u32 u; __builtin_memcpy(&u, &r, 4); return u;
}
#else
static __device__ __forceinline__ u32 pack2(float a, float b) {
  return (u32)f2bf(a) | ((u32)f2bf(b) << 16);
}
#endif
static __device__ __forceinline__ float bf_lo(u32 u) { return __uint_as_float(u << 16); }
static __device__ __forceinline__ float bf_hi(u32 u) { return __uint_as_float(u & 0xffff0000u); }

// gelu(x) ~= x * sigmoid(1.702 x); 1.702*log2(e) = 2.4555331
static __device__ __forceinline__ float gelu_fast(float x) {
  float e = __builtin_amdgcn_exp2f(x * -2.4555331f);
  return x * __builtin_amdgcn_rcpf(1.0f + e);
}

// max-reduce over the 16-lane DPP row (lanes l..l|15)
template <int CTRL>
static __device__ __forceinline__ float dppmax(float v) {
  int s = __builtin_bit_cast(int, v);
  int t = __builtin_amdgcn_update_dpp(s, s, CTRL, 0xf, 0xf, true);
  return fmaxf(v, __builtin_bit_cast(float, t));
}
static __device__ __forceinline__ float rowmax16(float v) {
  v = dppmax<0xB1>(v);   // quad_perm xor1
  v = dppmax<0x4E>(v);   // quad_perm xor2
  v = dppmax<0x141>(v);  // row_half_mirror
  v = dppmax<0x128>(v);  // row_ror:8
  return v;
}

// ---------- k_proj: xp = x @ W via MFMA (xp^T tiles), bf16-pair output ----------
// Also zeroes the BN partial-sum buffer (stream-ordered before k_lfa).
__global__ __launch_bounds__(256) void k_proj(const float* __restrict__ x,
                                              const float* __restrict__ W,
                                              u32* __restrict__ xp,
                                              float* __restrict__ part, int n) {
  const int t = threadIdx.x;
  if (blockIdx.x == 0 && t < 256) part[t] = 0.f;  // BN accumulator init

  __shared__ __align__(16) u32 Wf[8192];  // 32 frags (8 mt x 4 ks) x 256 u32
  for (int idx = t; idx < 8192; idx += 256) {
    int f = idx >> 8, rem = idx & 255;
    int l = rem >> 2, jp = rem & 3;
    int mt = f >> 2, ks = f & 3;
    int qq = l >> 4, mm = l & 15;
    int k = ks * 32 + qq * 8 + jp * 2;
    int c = mt * 16 + mm;
    Wf[idx] = pack2(W[(size_t)k * COUT + c], W[(size_t)(k + 1) * COUT + c]);
  }
  __syncthreads();

  const int wv = t >> 6, l = t & 63;
  const int q = l >> 4, m = l & 15;
  const short8* Wf8 = (const short8*)Wf;

  for (int tile = blockIdx.x * 4 + wv; tile * 16 < n; tile += gridDim.x * 4) {
    int r0 = tile * 16;
    int rr = min(r0 + m, n - 1);
    const float4* xr = (const float4*)(x + (size_t)rr * CIN);
    S8U xf[4];
#pragma unroll
    for (int ks = 0; ks < 4; ks++) {
      float4 a = xr[ks * 8 + q * 2];
      float4 b = xr[ks * 8 + q * 2 + 1];
      xf[ks].u[0] = pack2(a.x, a.y);
      xf[ks].u[1] = pack2(a.z, a.w);
      xf[ks].u[2] = pack2(b.x, b.y);
      xf[ks].u[3] = pack2(b.z, b.w);
    }
    bool ok = (r0 + m) < n;
    size_t rowb = (size_t)(r0 + m) * 64;
#pragma unroll
    for (int mt = 0; mt < 8; mt++) {
      f32x4 acc = {0.f, 0.f, 0.f, 0.f};
      __builtin_amdgcn_s_setprio(1);
#pragma unroll
      for (int ks = 0; ks < 4; ks++)
        acc = MFMA16(Wf8[(mt * 4 + ks) * 64 + l], xf[ks].s, acc);
      __builtin_amdgcn_s_setprio(0);
      if (ok) {
        uint2 v;
        v.x = pack2(acc[0], acc[1]);
        v.y = pack2(acc[2], acc[3]);
        *(uint2*)&xp[rowb + mt * 8 + q * 2] = v;
      }
    }
  }
}

// ---------- k_lfa: MFMA fused NCA + gather + max + BN-stats ----------
// v9 = v8 (r1 structure + setprio, 327 us verified) + fused BN statistics:
// the epilogue's float4 o is accumulated into a 1 KB LDS sum/sumsq array via
// ds_add_f32 (LDS pipe -- free in this VALU-bound kernel; only m==0 lanes
// active), flushed once per block with global f32 atomicAdd. Deletes the
// k_bnstats pass entirely.
// Design invariants (burned in over r2-r7):
//  - allocator budget is immovably 64 VGPR; register-resident transposes
//    spill GBs. LDS-scratch transposes also offload work to the idle LDS
//    pipe -- correct for a kernel at 68% VALUBusy.
//  - frag A-operands must stream from LDS (7 GB of re-reads) -> 117 KB LDS
//    -> 16 waves/CU is the structural occupancy cap.
__global__ __launch_bounds__(1024, 4) void k_lfa(
    const float* __restrict__ xyz, const u32* __restrict__ xp,
    const int* __restrict__ knn,
    const float* __restrict__ m1w, const float* __restrict__ m1b,
    const float* __restrict__ m2w, const float* __restrict__ m2b,
    const float* __restrict__ m3aw, const float* __restrict__ m3ab,
    const float* __restrict__ m3bw, const float* __restrict__ m3bb,
    float* __restrict__ xsmax, float* __restrict__ part, int n) {
  // [0,73728) frags (m2 f0..7, m3a f8..39, m3b f40..71), [73728,74752) w14,
  // [74752,76032) biases, [76032,116992) per-wave scratch 16 x 2560 B,
  // [116992,118016) BN sum/sumsq accumulators (128 + 128 floats)
  __shared__ __align__(16) char lds[118016];

  const int t = threadIdx.x, wv = t >> 6, l = t & 63;
  const int q = l >> 4, m = l & 15;

  {  // ---- per-block weight pack
    u32* lds32 = (u32*)lds;
    for (int idx = t; idx < 18432; idx += 1024) {
      int f = idx >> 8, rem = idx & 255;
      int ll = rem >> 2, jp = rem & 3;
      int qq = ll >> 4, mm = ll & 15;
      int j0 = jp * 2;
      float a, b;
      if (f < 8) {
        int mt = f >> 1, s = f & 1;
        const float* p = m2w + (size_t)(s * 32 + qq * 8 + j0) * D2 + mt * 16 + mm;
        a = p[0]; b = p[D2];
      } else if (f < 40) {
        int ff = f - 8; int mt = ff >> 2, s = ff & 3;
        const float* p = m3aw + (size_t)(s * 32 + qq * 8 + j0) * COUT + mt * 16 + mm;
        a = p[0]; b = p[COUT];
      } else {
        int ff = f - 40; int mt = ff >> 2, s = ff & 3;
        const float* p = m3bw + (size_t)(s * 32 + qq * 8 + j0) * COUT + mt * 16 + mm;
        a = p[0]; b = p[COUT];
      }
      lds32[idx] = pack2(a, b);
    }
    if (t < 64) {
      int p = (t & 32) + (t & 7) * 4 + ((t >> 3) & 3);
      ((float4*)(lds + 73728))[p] = make_float4(m1w[t], m1w[64 + t], m1w[128 + t], m1b[t]);
    }
    if (t < 320) {
      float* bias = (float*)(lds + 74752);
      bias[t] = (t < 64) ? m2b[t] : (t < 192) ? m3ab[t - 64] : m3bb[t - 192];
    }
    if (t < 256) ((float*)(lds + 116992))[t] = 0.f;  // BN accumulators
  }
  __syncthreads();

  const char* fr = lds;
  const float4* w14 = (const float4*)(lds + 73728);
  const float* bias = (const float*)(lds + 74752);
  float* bn = (float*)(lds + 116992);
  char* sA = lds + 76032 + wv * 2560;
  char* sB = sA + 1280;

  for (int pr = blockIdx.x * 16 + wv; pr * 2 < n; pr += gridDim.x * 16) {
    const int ptA = pr * 2;
    const int ptB = ptA + 1;
    const bool hasB = ptB < n;
    const int ptBc = hasB ? ptB : ptA;
    const int kidA = knn[(size_t)ptA * KNN + m];
    const int kidB = knn[(size_t)ptBc * KNN + m];

    // ---- prefetch epilogue gathers (compiler may sink; harmless)
    uint2 gA[8], gB[8];
#pragma unroll
    for (int mt = 0; mt < 8; mt++) {
      gA[mt] = *(const uint2*)(xp + (size_t)kidA * 64 + mt * 8 + q * 2);
      gB[mt] = *(const uint2*)(xp + (size_t)kidB * 64 + mt * 8 + q * 2);
    }

    float pxA = xyz[ptA * 3 + 0], pyA = xyz[ptA * 3 + 1], pzA = xyz[ptA * 3 + 2];
    float pxB = xyz[ptBc * 3 + 0], pyB = xyz[ptBc * 3 + 1], pzB = xyz[ptBc * 3 + 2];
    float axA = xyz[kidA * 3 + 0] - pxA, ayA = xyz[kidA * 3 + 1] - pyA, azA = xyz[kidA * 3 + 2] - pzA;
    float axB = xyz[kidB * 3 + 0] - pxB, ayB = xyz[kidB * 3 + 1] - pyB, azB = xyz[kidB * 3 + 2] - pzB;

    // ---- p0 rows in B-frag layout (registers)
    float p0A[16], p0B[16];
#pragma unroll
    for (int s = 0; s < 2; s++)
#pragma unroll
      for (int j = 0; j < 8; j++) {
        float4 w = w14[s * 32 + j * 4 + q];
        p0A[s * 8 + j] = fmaf(axA, w.x, fmaf(ayA, w.y, fmaf(azA, w.z, w.w)));
        p0B[s * 8 + j] = fmaf(axB, w.x, fmaf(ayB, w.y, fmaf(azB, w.z, w.w)));
      }
    S8U bp0A[2], bp0B[2], bplA[2], bplB[2];
#pragma unroll
    for (int s = 0; s < 2; s++)
#pragma unroll
      for (int jj = 0; jj < 4; jj++) {
        bp0A[s].u[jj] = pack2(p0A[s * 8 + 2 * jj], p0A[s * 8 + 2 * jj + 1]);
        bp0B[s].u[jj] = pack2(p0B[s * 8 + 2 * jj], p0B[s * 8 + 2 * jj + 1]);
      }
#pragma unroll
    for (int i = 0; i < 16; i++) { p0A[i] = rowmax16(p0A[i]); p0B[i] = rowmax16(p0B[i]); }
#pragma unroll
    for (int s = 0; s < 2; s++)
#pragma unroll
      for (int jj = 0; jj < 4; jj++) {
        bplA[s].u[jj] = pack2(p0A[s * 8 + 2 * jj], p0A[s * 8 + 2 * jj + 1]);
        bplB[s].u[jj] = pack2(p0B[s * 8 + 2 * jj], p0B[s * 8 + 2 * jj + 1]);
      }

    // ---- m2 -> p1 (sliced scratch) -> bpf frags
    short8 bpfA[2], bpfB[2];
#pragma unroll
    for (int s = 0; s < 2; s++) {
#pragma unroll
      for (int h = 0; h < 2; h++) {
        int mt = 2 * s + h;
        float4 bb = *(const float4*)&bias[mt * 16 + q * 4];
        f32x4 accA = {bb.x, bb.y, bb.z, bb.w};
        f32x4 accB = accA;
        __builtin_amdgcn_s_setprio(1);
#pragma unroll
        for (int ks = 0; ks < 2; ks++) {
          short8 af = *(const short8*)(fr + (mt * 2 + ks) * 1024 + l * 16);
          accA = MFMA16(af, bp0A[ks].s, accA);
          accB = MFMA16(af, bp0B[ks].s, accB);
        }
        __builtin_amdgcn_s_setprio(0);
        uint2 wA; wA.x = pack2(accA[0], accA[1]); wA.y = pack2(accA[2], accA[3]);
        uint2 wB; wB.x = pack2(accB[0], accB[1]); wB.y = pack2(accB[2], accB[3]);
        *(uint2*)(sA + m * 80 + h * 32 + q * 8) = wA;
        *(uint2*)(sB + m * 80 + h * 32 + q * 8) = wB;
      }
      bpfA[s] = *(const short8*)(sA + m * 80 + q * 16);
      bpfB[s] = *(const short8*)(sB + m * 80 + q * 16);
    }

    // ---- m3a -> gelu -> g (sliced scratch) -> bg frags
    short8 bgA[4], bgB[4];
#pragma unroll
    for (int s = 0; s < 4; s++) {
#pragma unroll
      for (int h = 0; h < 2; h++) {
        int mt = 2 * s + h;
        float4 bb = *(const float4*)&bias[64 + mt * 16 + q * 4];
        f32x4 accA = {bb.x, bb.y, bb.z, bb.w};
        f32x4 accB = accA;
        __builtin_amdgcn_s_setprio(1);
#pragma unroll
        for (int ks = 0; ks < 4; ks++) {
          short8 af = *(const short8*)(fr + (8 + mt * 4 + ks) * 1024 + l * 16);
          short8 bA = (ks == 0) ? bpfA[0] : (ks == 1) ? bpfA[1] : (ks == 2) ? bplA[0].s : bplA[1].s;
          short8 bB = (ks == 0) ? bpfB[0] : (ks == 1) ? bpfB[1] : (ks == 2) ? bplB[0].s : bplB[1].s;
          accA = MFMA16(af, bA, accA);
          accB = MFMA16(af, bB, accB);
        }
        __builtin_amdgcn_s_setprio(0);
        uint2 wA; wA.x = pack2(gelu_fast(accA[0]), gelu_fast(accA[1]));
        wA.y = pack2(gelu_fast(accA[2]), gelu_fast(accA[3]));
        uint2 wB; wB.x = pack2(gelu_fast(accB[0]), gelu_fast(accB[1]));
        wB.y = pack2(gelu_fast(accB[2]), gelu_fast(accB[3]));
        *(uint2*)(sA + m * 80 + h * 32 + q * 8) = wA;
        *(uint2*)(sB + m * 80 + h * 32 + q * 8) = wB;
      }
      bgA[s] = *(const short8*)(sA + m * 80 + q * 16);
      bgB[s] = *(const short8*)(sB + m * 80 + q * 16);
    }

    // ---- m3b + fused epilogue (pe in regs; gathers in gA/gB; BN stats in LDS)
#pragma unroll
    for (int mt = 0; mt < 8; mt++) {
      float4 bb = *(const float4*)&bias[192 + mt * 16 + q * 4];
      f32x4 accA = {bb.x, bb.y, bb.z, bb.w};
      f32x4 accB = accA;
      __builtin_amdgcn_s_setprio(1);
#pragma unroll
      for (int ks = 0; ks < 4; ks++) {
        short8 af = *(const short8*)(fr + (40 + mt * 4 + ks) * 1024 + l * 16);
        accA = MFMA16(af, bgA[ks], accA);
        accB = MFMA16(af, bgB[ks], accB);
      }
      __builtin_amdgcn_s_setprio(0);
      {
        // self-row load: uniform in m -> broadcast; issued before the rowmax
        // chain so its latency hides under the DPP-max ops.
        uint2 sf = *(const uint2*)(xp + (size_t)ptA * 64 + mt * 8 + q * 2);
        float v0 = bf_lo(gA[mt].x) + accA[0];
        float v1 = bf_hi(gA[mt].x) + accA[1];
        float v2 = bf_lo(gA[mt].y) + accA[2];
        float v3 = bf_hi(gA[mt].y) + accA[3];
        v0 = rowmax16(v0); v1 = rowmax16(v1); v2 = rowmax16(v2); v3 = rowmax16(v3);
        if (m == 0) {
          float4 o = make_float4(v0 - bf_lo(sf.x), v1 - bf_hi(sf.x),
                                 v2 - bf_lo(sf.y), v3 - bf_hi(sf.y));
          *(float4*)&xsmax[(size_t)ptA * COUT + mt * 16 + q * 4] = o;
          int c = mt * 16 + q * 4;
          atomicAdd(&bn[c + 0], o.x); atomicAdd(&bn[c + 1], o.y);
          atomicAdd(&bn[c + 2], o.z); atomicAdd(&bn[c + 3], o.w);
          atomicAdd(&bn[128 + c + 0], o.x * o.x); atomicAdd(&bn[128 + c + 1], o.y * o.y);
          atomicAdd(&bn[128 + c + 2], o.z * o.z); atomicAdd(&bn[128 + c + 3], o.w * o.w);
        }
      }
      {
        uint2 sf = *(const uint2*)(xp + (size_t)ptBc * 64 + mt * 8 + q * 2);
        float v0 = bf_lo(gB[mt].x) + accB[0];
        float v1 = bf_hi(gB[mt].x) + accB[1];
        float v2 = bf_lo(gB[mt].y) + accB[2];
        float v3 = bf_hi(gB[mt].y) + accB[3];
        v0 = rowmax16(v0); v1 = rowmax16(v1); v2 = rowmax16(v2); v3 = rowmax16(v3);
        if (hasB && m == 0) {
          float4 o = make_float4(v0 - bf_lo(sf.x), v1 - bf_hi(sf.x),
                                 v2 - bf_lo(sf.y), v3 - bf_hi(sf.y));
          *(float4*)&xsmax[(size_t)ptB * COUT + mt * 16 + q * 4] = o;
          int c = mt * 16 + q * 4;
          atomicAdd(&bn[c + 0], o.x); atomicAdd(&bn[c + 1], o.y);
          atomicAdd(&bn[c + 2], o.z); atomicAdd(&bn[c + 3], o.w);
          atomicAdd(&bn[128 + c + 0], o.x * o.x); atomicAdd(&bn[128 + c + 1], o.y * o.y);
          atomicAdd(&bn[128 + c + 2], o.z * o.z); atomicAdd(&bn[128 + c + 3], o.w * o.w);
        }
      }
    }
  }

  // ---- flush BN partial sums (one global atomic per channel per block)
  __syncthreads();
  if (t < 256) atomicAdd(&part[t], bn[t]);
}

// ---------- BN stage 2: finalize mean/invstd from the fused sums ----------
__global__ void k_bnfinal(const float* __restrict__ part, float* __restrict__ ms,
                          int n) {
  int c = threadIdx.x;  // 128 threads
  float s = part[c];
  float s2 = part[128 + c];
  float inv_n = 1.0f / (float)n;
  float mean = s * inv_n;
  float var = s2 * inv_n - mean * mean;
  ms[c] = mean;
  ms[128 + c] = rsqrtf(var + EPS);
}

// ---------- BN normalize ----------
__global__ __launch_bounds__(256) void k_bnnorm(const float* __restrict__ xs,
                                                const float* __restrict__ ms,
                                                const float* __restrict__ gamma,
                                                const float* __restrict__ beta,
                                                float* __restrict__ out, int n) {
  size_t i = (size_t)blockIdx.x * 256 + threadIdx.x;
  size_t total4 = (size_t)n * (COUT / 4);
  if (i >= total4) return;
  int c = (int)((i * 4) & (COUT - 1));
  float4 v = ((const float4*)xs)[i];
  float4 mn = *(const float4*)&ms[c];
  float4 iv = *(const float4*)&ms[128 + c];
  float4 gm = *(const float4*)&gamma[c];
  float4 bt = *(const float4*)&beta[c];
  float4 o;
  o.x = (v.x - mn.x) * iv.x * gm.x + bt.x;
  o.y = (v.y - mn.y) * iv.y * gm.y + bt.y;
  o.z = (v.z - mn.z) * iv.z * gm.z + bt.z;
  o.w = (v.w - mn.w) * iv.w * gm.w + bt.w;
  ((float4*)out)[i] = o;
}

// ---------- launch ----------
extern "C" void kernel_launch(void* const* d_in, const int* in_sizes, int n_in,
                              void* d_out, int out_size, void* d_ws, size_t ws_size,
                              hipStream_t stream) {
  const float* xyz = (const float*)d_in[0];
  const float* x = (const float*)d_in[1];
  const int* knn = (const int*)d_in[2];
  const float* W = (const float*)d_in[3];
  const float* m1w = (const float*)d_in[4];
  const float* m1b = (const float*)d_in[5];
  const float* m2w = (const float*)d_in[6];
  const float* m2b = (const float*)d_in[7];
  const float* m3aw = (const float*)d_in[8];
  const float* m3ab = (const float*)d_in[9];
  const float* m3bw = (const float*)d_in[10];
  const float* m3bb = (const float*)d_in[11];
  const float* gamma = (const float*)d_in[12];
  const float* beta = (const float*)d_in[13];
  float* out = (float*)d_out;

  int n = in_sizes[0] / 3;

  char* ws = (char*)d_ws;
  u32* xp = (u32*)ws;                       // n * 256 B
  size_t o1 = (((size_t)n * 256 + 255) & ~(size_t)255);
  float* xsm = (float*)(ws + o1);           // n * 512 B
  size_t o2 = o1 + (((size_t)n * 512 + 255) & ~(size_t)255);
  float* part = (float*)(ws + o2);          // 256 floats (sum | sumsq)
  size_t o3 = o2 + 524288;
  float* ms = (float*)(ws + o3);            // 256 floats (mean | invstd)

  k_proj<<<1024, 256, 0, stream>>>(x, W, xp, part, n);
  k_lfa<<<256, 1024, 0, stream>>>(xyz, xp, knn, m1w, m1b, m2w, m2b,
                                  m3aw, m3ab, m3bw, m3bb, xsm, part, n);
  k_bnfinal<<<1, 128, 0, stream>>>(part, ms, n);
  k_bnnorm<<<(int)(((size_t)n * (COUT / 4) + 255) / 256), 256, 0, stream>>>(
      xsm, ms, gamma, beta, out, n);
}